// Round 1
// baseline (649.186 us; speedup 1.0000x reference)
//
#include <hip/hip_runtime.h>
#include <hip/hip_bf16.h>

// ---------------- graph build ----------------

__global__ void k_hist(const int* __restrict__ dst, int* __restrict__ degcnt, int E) {
    int e = blockIdx.x * 256 + threadIdx.x;
    if (e < E) atomicAdd(&degcnt[dst[e]], 1);
}

__global__ void k_dinv(const int* __restrict__ degcnt, float* __restrict__ dinv, int n) {
    int i = blockIdx.x * 256 + threadIdx.x;
    if (i < n) dinv[i] = rsqrtf((float)(degcnt[i] + 1));  // +1 self-loop
}

__global__ void k_scan1(const int* __restrict__ degcnt, int* __restrict__ row_start,
                        int* __restrict__ bsum, int n) {
    __shared__ int s[256];
    int i = blockIdx.x * 256 + threadIdx.x;
    int v = (i < n) ? degcnt[i] : 0;
    s[threadIdx.x] = v;
    __syncthreads();
    for (int off = 1; off < 256; off <<= 1) {
        int x = (threadIdx.x >= off) ? s[threadIdx.x - off] : 0;
        __syncthreads();
        s[threadIdx.x] += x;
        __syncthreads();
    }
    if (i < n) row_start[i] = s[threadIdx.x] - v;   // block-local exclusive
    if (threadIdx.x == 255) bsum[blockIdx.x] = s[255];
}

__global__ void k_scan2(int* __restrict__ bsum, int nb) {
    __shared__ int s[256];
    int t = threadIdx.x;
    int v = (t < nb) ? bsum[t] : 0;
    s[t] = v;
    __syncthreads();
    for (int off = 1; off < 256; off <<= 1) {
        int x = (t >= off) ? s[t - off] : 0;
        __syncthreads();
        s[t] += x;
        __syncthreads();
    }
    if (t < nb) bsum[t] = s[t] - v;                 // exclusive block offsets
}

__global__ void k_scan3(int* __restrict__ row_start, const int* __restrict__ bsum,
                        int* __restrict__ cursor, int n, int E) {
    int i = blockIdx.x * 256 + threadIdx.x;
    if (i < n) {
        int v = row_start[i] + bsum[blockIdx.x];
        row_start[i] = v;
        cursor[i] = v;
    }
    if (i == 0) row_start[n] = E;
}

__global__ void k_fill(const int* __restrict__ src, const int* __restrict__ dst,
                       int* __restrict__ cursor, int* __restrict__ csr, int E) {
    int e = blockIdx.x * 256 + threadIdx.x;
    if (e < E) {
        int p = atomicAdd(&cursor[dst[e]], 1);
        csr[p] = src[e];
    }
}

// ---------------- dense GEMM: H[row] = (X[row] @ W) * dinv[row] ----------------
// 256 threads, 16 rows/block; W staged in LDS (K-tiled to stay <=32KB).

template <int K, int F>
__global__ void k_gemm_scale(const float* __restrict__ X, const float* __restrict__ W,
                             const float* __restrict__ dinv, float* __restrict__ H, int n) {
    constexpr int ROWS = 16;
    constexpr int TPR  = 256 / ROWS;       // threads per row = 16
    constexpr int CPT  = F / TPR;          // cols per thread (8 / 4)
    constexpr int CV   = CPT / 4;          // float4 per thread (2 / 1)
    constexpr int KT   = (K * F * 4 > 32768) ? (K / 2) : K;
    constexpr int NKT  = K / KT;
    __shared__ float sW[KT * F];
    __shared__ float sX[ROWS * (K + 4)];   // +4 pad breaks bank aliasing

    int row0 = blockIdx.x * ROWS;
    for (int i = threadIdx.x; i < ROWS * K; i += 256) {
        int r = i / K, k = i - r * K;
        int gr = row0 + r;
        sX[r * (K + 4) + k] = (gr < n) ? X[(size_t)gr * K + k] : 0.f;
    }

    int r  = threadIdx.x / TPR;
    int cg = threadIdx.x % TPR;
    float4 acc[CV];
#pragma unroll
    for (int c = 0; c < CV; ++c) acc[c] = make_float4(0.f, 0.f, 0.f, 0.f);

    for (int t = 0; t < NKT; ++t) {
        __syncthreads();
        for (int i = threadIdx.x; i < KT * F; i += 256) sW[i] = W[t * KT * F + i];
        __syncthreads();
        const float4* sW4 = (const float4*)sW;
#pragma unroll 4
        for (int kk = 0; kk < KT; ++kk) {
            float xv = sX[r * (K + 4) + t * KT + kk];
#pragma unroll
            for (int c = 0; c < CV; ++c) {
                float4 w = sW4[kk * (F / 4) + cg * CV + c];
                acc[c].x = fmaf(xv, w.x, acc[c].x);
                acc[c].y = fmaf(xv, w.y, acc[c].y);
                acc[c].z = fmaf(xv, w.z, acc[c].z);
                acc[c].w = fmaf(xv, w.w, acc[c].w);
            }
        }
    }

    int gr = row0 + r;
    if (gr < n) {
        float dv = dinv[gr];
        float4* Hp = (float4*)(H + (size_t)gr * F);
#pragma unroll
        for (int c = 0; c < CV; ++c) {
            float4 o = acc[c];
            o.x *= dv; o.y *= dv; o.z *= dv; o.w *= dv;
            Hp[cg * CV + c] = o;
        }
    }
}

// ---------------- CSR aggregate + bias + relu ----------------
// out[i] = relu(dinv[i] * (hn[i] + sum_{j in csr row} hn[j]) + b)
// One F/4-lane sub-group per node, float4 per lane.

template <int F>
__global__ void k_agg(const float* __restrict__ HN, const int* __restrict__ csr,
                      const int* __restrict__ rs, const float* __restrict__ dinv,
                      const float* __restrict__ bias, float* __restrict__ OUT, int n) {
    constexpr int LPN = F / 4;             // lanes per node (32 / 16)
    constexpr int NPB = 256 / LPN;         // nodes per block (8 / 16)
    int node = blockIdx.x * NPB + threadIdx.x / LPN;
    int l    = threadIdx.x % LPN;
    if (node >= n) return;
    const float4* hn4 = (const float4*)HN;
    size_t base = (size_t)node * LPN + l;
    float4 acc = hn4[base];                // self loop (hn already *dinv[self])
    int s = rs[node], e = rs[node + 1];
    int k = s;
    for (; k + 2 <= e; k += 2) {
        int s0 = csr[k], s1 = csr[k + 1];
        float4 a = hn4[(size_t)s0 * LPN + l];
        float4 b = hn4[(size_t)s1 * LPN + l];
        acc.x += a.x + b.x; acc.y += a.y + b.y;
        acc.z += a.z + b.z; acc.w += a.w + b.w;
    }
    if (k < e) {
        float4 a = hn4[(size_t)csr[k] * LPN + l];
        acc.x += a.x; acc.y += a.y; acc.z += a.z; acc.w += a.w;
    }
    float dv = dinv[node];
    float4 bb = ((const float4*)bias)[l];
    float4 o;
    o.x = fmaxf(fmaf(acc.x, dv, bb.x), 0.f);
    o.y = fmaxf(fmaf(acc.y, dv, bb.y), 0.f);
    o.z = fmaxf(fmaf(acc.z, dv, bb.z), 0.f);
    o.w = fmaxf(fmaf(acc.w, dv, bb.w), 0.f);
    ((float4*)OUT)[base] = o;
}

// ---------------- pooling + head ----------------

__global__ void k_pool(const float* __restrict__ H3, const int* __restrict__ batch,
                       float* __restrict__ gsum, int* __restrict__ gcnt, int n) {
    int i = blockIdx.x * 4 + (threadIdx.x >> 6);
    int lane = threadIdx.x & 63;
    if (i >= n) return;
    int b = batch[i];
    atomicAdd(&gsum[b * 64 + lane], H3[(size_t)i * 64 + lane]);
    if (lane == 0) atomicAdd(&gcnt[b], 1);
}

__global__ void k_head(const float* __restrict__ gsum, const int* __restrict__ gcnt,
                       const float* __restrict__ Wl1, const float* __restrict__ bl1,
                       const float* __restrict__ Wl2, const float* __restrict__ bl2,
                       float* __restrict__ out, int nb) {
    __shared__ float sh[4][64];
    __shared__ float shid[4][32];
    int w = threadIdx.x >> 6;
    int lane = threadIdx.x & 63;
    int row = blockIdx.x * 4 + w;
    if (row < nb) {
        float cnt = fmaxf((float)gcnt[row], 1.f);
        sh[w][lane] = gsum[row * 64 + lane] / cnt;
    }
    __syncthreads();
    if (row < nb && lane < 32) {
        float a = bl1[lane];
        for (int k = 0; k < 64; ++k) a = fmaf(sh[w][k], Wl1[k * 32 + lane], a);
        shid[w][lane] = fmaxf(a, 0.f);
    }
    __syncthreads();
    if (row < nb && lane < 10) {
        float a = bl2[lane];
        for (int k = 0; k < 32; ++k) a = fmaf(shid[w][k], Wl2[k * 10 + lane], a);
        out[row * 10 + lane] = a;
    }
}

// ---------------- launch ----------------

extern "C" void kernel_launch(void* const* d_in, const int* in_sizes, int n_in,
                              void* d_out, int out_size, void* d_ws, size_t ws_size,
                              hipStream_t stream) {
    const float* x    = (const float*)d_in[0];
    const int*   ei   = (const int*)d_in[1];
    const int*   batch= (const int*)d_in[2];
    const float* W1   = (const float*)d_in[3];
    const float* b1   = (const float*)d_in[4];
    const float* W2   = (const float*)d_in[5];
    const float* b2   = (const float*)d_in[6];
    const float* W3   = (const float*)d_in[7];
    const float* b3   = (const float*)d_in[8];
    const float* Wl1  = (const float*)d_in[9];
    const float* bl1  = (const float*)d_in[10];
    const float* Wl2  = (const float*)d_in[11];
    const float* bl2  = (const float*)d_in[12];

    const int N = in_sizes[0] / 64;
    const int E = in_sizes[1] / 2;
    const int B = out_size / 10;
    const int* srcI = ei;
    const int* dstI = ei + E;

    char* p = (char*)d_ws;
    auto alloc = [&](size_t bytes) {
        char* r = p;
        p += (bytes + 255) & ~(size_t)255;
        return r;
    };
    int*   degcnt    = (int*)alloc((size_t)N * 4);
    float* gsum      = (float*)alloc((size_t)B * 64 * 4);
    int*   gcnt      = (int*)alloc((size_t)B * 4);
    size_t zbytes    = (size_t)(p - (char*)d_ws);   // zero-init prefix
    float* dinv      = (float*)alloc((size_t)N * 4);
    int*   row_start = (int*)alloc((size_t)(N + 1) * 4);
    int*   cursor    = (int*)alloc((size_t)N * 4);
    int*   bsum      = (int*)alloc(1024 * 4);
    int*   csr       = (int*)alloc((size_t)E * 4);
    float* bufA      = (float*)alloc((size_t)N * 128 * 4);
    float* bufB      = (float*)alloc((size_t)N * 128 * 4);

    hipMemsetAsync(d_ws, 0, zbytes, stream);

    int gE = (E + 255) / 256;
    int gN = (N + 255) / 256;
    k_hist <<<gE, 256, 0, stream>>>(dstI, degcnt, E);
    k_dinv <<<gN, 256, 0, stream>>>(degcnt, dinv, N);
    k_scan1<<<gN, 256, 0, stream>>>(degcnt, row_start, bsum, N);
    k_scan2<<<1, 256, 0, stream>>>(bsum, gN);
    k_scan3<<<gN, 256, 0, stream>>>(row_start, bsum, cursor, N, E);
    k_fill <<<gE, 256, 0, stream>>>(srcI, dstI, cursor, csr, E);

    k_gemm_scale<64, 128><<<(N + 15) / 16, 256, 0, stream>>>(x, W1, dinv, bufA, N);
    k_agg<128><<<(N + 7) / 8, 256, 0, stream>>>(bufA, csr, row_start, dinv, b1, bufB, N);
    k_gemm_scale<128, 128><<<(N + 15) / 16, 256, 0, stream>>>(bufB, W2, dinv, bufA, N);
    k_agg<128><<<(N + 7) / 8, 256, 0, stream>>>(bufA, csr, row_start, dinv, b2, bufB, N);
    k_gemm_scale<128, 64><<<(N + 15) / 16, 256, 0, stream>>>(bufB, W3, dinv, bufA, N);
    k_agg<64><<<(N + 15) / 16, 256, 0, stream>>>(bufA, csr, row_start, dinv, b3, bufB, N);

    k_pool<<<(N + 3) / 4, 256, 0, stream>>>(bufB, batch, gsum, gcnt, N);
    k_head<<<(B + 3) / 4, 256, 0, stream>>>(gsum, gcnt, Wl1, bl1, Wl2, bl2, (float*)d_out, B);
}

// Round 2
// 586.404 us; speedup vs baseline: 1.1071x; 1.1071x over previous
//
#include <hip/hip_runtime.h>
#include <hip/hip_bf16.h>
#include <hip/hip_fp16.h>

// ============ graph build: bucketed counting sort by dst ============
// cursor-bucket = dst>>4 (16 nodes); workgroup window = 64 nodes (4 buckets).
// packed record = (src<<6) | (dst&63)   [src < 2^16, window 64-aligned]

__global__ void k_bhist(const int* __restrict__ dst, int* __restrict__ bcnt, int E) {
    int e = blockIdx.x * 256 + threadIdx.x;
    if (e < E) atomicAdd(&bcnt[dst[e] >> 4], 1);
}

__global__ void k_bscan(const int* __restrict__ bcnt, int* __restrict__ bstart,
                        int* __restrict__ bcur, int nb) {
    __shared__ int s[1024];
    int t = threadIdx.x;
    int carry = 0;
    for (int base = 0; base < nb; base += 1024) {
        int i = base + t;
        int v = (i < nb) ? bcnt[i] : 0;
        s[t] = v;
        __syncthreads();
        for (int off = 1; off < 1024; off <<= 1) {
            int x = (t >= off) ? s[t - off] : 0;
            __syncthreads();
            s[t] += x;
            __syncthreads();
        }
        if (i < nb) { int ex = carry + s[t] - v; bstart[i] = ex; bcur[i] = ex; }
        int tot = s[1023];
        __syncthreads();
        carry += tot;
    }
    if (t == 0) bstart[nb] = carry;
}

__global__ void k_binfill(const int* __restrict__ src, const int* __restrict__ dst,
                          int* __restrict__ bcur, int* __restrict__ packed, int E) {
    int e = blockIdx.x * 256 + threadIdx.x;
    if (e < E) {
        int d = dst[e];
        int p = atomicAdd(&bcur[d >> 4], 1);
        packed[p] = (src[e] << 6) | (d & 63);
    }
}

// per-64-node window: count deg from packed (no global atomics), emit dinv
__global__ void k_bcount(const int* __restrict__ packed, const int* __restrict__ bstart,
                         int* __restrict__ degcnt, float* __restrict__ dinv, int n, int nb) {
    __shared__ int cnt[64];
    int w = blockIdx.x;
    if (threadIdx.x < 64) cnt[threadIdx.x] = 0;
    __syncthreads();
    int b0 = w * 4;
    int s = bstart[b0];
    int e = bstart[min(b0 + 4, nb)];
    for (int k = s + threadIdx.x; k < e; k += 256)
        atomicAdd(&cnt[packed[k] & 63], 1);
    __syncthreads();
    int node = w * 64 + threadIdx.x;
    if (threadIdx.x < 64 && node < n) {
        int c = cnt[threadIdx.x];
        degcnt[node] = c;
        dinv[node] = rsqrtf((float)(c + 1));   // +1 self-loop
    }
}

__global__ void k_scan1(const int* __restrict__ degcnt, int* __restrict__ row_start,
                        int* __restrict__ bsum, int n) {
    __shared__ int s[256];
    int i = blockIdx.x * 256 + threadIdx.x;
    int v = (i < n) ? degcnt[i] : 0;
    s[threadIdx.x] = v;
    __syncthreads();
    for (int off = 1; off < 256; off <<= 1) {
        int x = (threadIdx.x >= off) ? s[threadIdx.x - off] : 0;
        __syncthreads();
        s[threadIdx.x] += x;
        __syncthreads();
    }
    if (i < n) row_start[i] = s[threadIdx.x] - v;
    if (threadIdx.x == 255) bsum[blockIdx.x] = s[255];
}

__global__ void k_scan2(int* __restrict__ bsum, int nb) {
    __shared__ int s[256];
    int t = threadIdx.x;
    int v = (t < nb) ? bsum[t] : 0;
    s[t] = v;
    __syncthreads();
    for (int off = 1; off < 256; off <<= 1) {
        int x = (t >= off) ? s[t - off] : 0;
        __syncthreads();
        s[t] += x;
        __syncthreads();
    }
    if (t < nb) bsum[t] = s[t] - v;
}

__global__ void k_scan3(int* __restrict__ row_start, const int* __restrict__ bsum,
                        int n, int E) {
    int i = blockIdx.x * 256 + threadIdx.x;
    if (i < n) row_start[i] += bsum[blockIdx.x];
    if (i == 0) row_start[n] = E;
}

// per-64-node window: LDS cursors, write csr grouped-by-node (contiguous ~8KB window)
__global__ void k_csrfill(const int* __restrict__ packed, const int* __restrict__ bstart,
                          const int* __restrict__ rs, int* __restrict__ csr, int n, int nb) {
    __shared__ int cur[64];
    int w = blockIdx.x;
    int node = w * 64 + threadIdx.x;
    if (threadIdx.x < 64) cur[threadIdx.x] = (node < n) ? rs[node] : 0;
    __syncthreads();
    int b0 = w * 4;
    int s = bstart[b0];
    int e = bstart[min(b0 + 4, nb)];
    for (int k = s + threadIdx.x; k < e; k += 256) {
        int v = packed[k];
        int p = atomicAdd(&cur[v & 63], 1);
        csr[p] = v >> 6;
    }
}

// ============ dense GEMM: H[row] = fp16( (X[row] @ W) * dinv[row] ) ============

template <int K, int F, bool HIN>
__global__ void k_gemm_scale(const void* __restrict__ Xv, const float* __restrict__ W,
                             const float* __restrict__ dinv, __half* __restrict__ H, int n) {
    constexpr int ROWS = 16;
    constexpr int TPR  = 16;
    constexpr int CPT  = F / TPR;          // 8 / 4
    constexpr int CV   = CPT / 4;          // 2 / 1
    constexpr int KT   = (K * F * 4 > 32768) ? (K / 2) : K;
    constexpr int NKT  = K / KT;
    __shared__ float sW[KT * F];
    __shared__ float sX[ROWS * (K + 4)];

    int row0 = blockIdx.x * ROWS;
    if (HIN) {
        const uint4* X = (const uint4*)Xv;          // 8 halves per load
        for (int i = threadIdx.x; i < ROWS * (K / 8); i += 256) {
            int r = i / (K / 8), k8 = i % (K / 8);
            int gr = row0 + r;
            uint4 v = (gr < n) ? X[(size_t)gr * (K / 8) + k8] : make_uint4(0, 0, 0, 0);
            const __half2* h2 = (const __half2*)&v;
            float* dp = &sX[r * (K + 4) + k8 * 8];
#pragma unroll
            for (int j = 0; j < 4; ++j) {
                float2 f = __half22float2(h2[j]);
                dp[2 * j] = f.x; dp[2 * j + 1] = f.y;
            }
        }
    } else {
        const float4* X = (const float4*)Xv;
        for (int i = threadIdx.x; i < ROWS * (K / 4); i += 256) {
            int r = i / (K / 4), k4 = i % (K / 4);
            int gr = row0 + r;
            float4 v = (gr < n) ? X[(size_t)gr * (K / 4) + k4] : make_float4(0.f, 0.f, 0.f, 0.f);
            float* dp = &sX[r * (K + 4) + k4 * 4];
            dp[0] = v.x; dp[1] = v.y; dp[2] = v.z; dp[3] = v.w;
        }
    }

    int r  = threadIdx.x / TPR;
    int cg = threadIdx.x % TPR;
    float4 acc[CV];
#pragma unroll
    for (int c = 0; c < CV; ++c) acc[c] = make_float4(0.f, 0.f, 0.f, 0.f);

    for (int t = 0; t < NKT; ++t) {
        __syncthreads();
        for (int i = threadIdx.x; i < KT * F; i += 256) sW[i] = W[t * KT * F + i];
        __syncthreads();
        const float4* sW4 = (const float4*)sW;
#pragma unroll 4
        for (int kk = 0; kk < KT; ++kk) {
            float xv = sX[r * (K + 4) + t * KT + kk];
#pragma unroll
            for (int c = 0; c < CV; ++c) {
                float4 w = sW4[kk * (F / 4) + cg * CV + c];
                acc[c].x = fmaf(xv, w.x, acc[c].x);
                acc[c].y = fmaf(xv, w.y, acc[c].y);
                acc[c].z = fmaf(xv, w.z, acc[c].z);
                acc[c].w = fmaf(xv, w.w, acc[c].w);
            }
        }
    }

    int gr = row0 + r;
    if (gr < n) {
        float dv = dinv[gr];
#pragma unroll
        for (int c = 0; c < CV; ++c) {
            __half2 h0 = __floats2half2_rn(acc[c].x * dv, acc[c].y * dv);
            __half2 h1 = __floats2half2_rn(acc[c].z * dv, acc[c].w * dv);
            uint2 u;
            u.x = *(unsigned int*)&h0;
            u.y = *(unsigned int*)&h1;
            *(uint2*)(H + (size_t)gr * F + cg * CPT + c * 4) = u;
        }
    }
}

// ============ CSR aggregate (fp16 gather) + bias + relu ============

__device__ __forceinline__ void acc8(float* a, uint4 v) {
    const __half2* h = (const __half2*)&v;
#pragma unroll
    for (int i = 0; i < 4; ++i) {
        float2 f = __half22float2(h[i]);
        a[2 * i]     += f.x;
        a[2 * i + 1] += f.y;
    }
}

template <int F>
__global__ void k_agg_h(const __half* __restrict__ HN, const int* __restrict__ csr,
                        const int* __restrict__ rs, const float* __restrict__ dinv,
                        const float* __restrict__ bias, __half* __restrict__ OUT, int n) {
    constexpr int LPN = F / 8;             // lanes per node (16 / 8)
    constexpr int NPB = 256 / LPN;         // nodes per block (16 / 32)
    int node = blockIdx.x * NPB + threadIdx.x / LPN;
    int l    = threadIdx.x % LPN;
    if (node >= n) return;
    const uint4* hn = (const uint4*)HN;
    size_t base = (size_t)node * LPN + l;
    float a[8];
    {
        uint4 v = hn[base];                // self (hn already *dinv[self])
        const __half2* h = (const __half2*)&v;
#pragma unroll
        for (int i = 0; i < 4; ++i) {
            float2 f = __half22float2(h[i]);
            a[2 * i] = f.x; a[2 * i + 1] = f.y;
        }
    }
    int s = rs[node], e = rs[node + 1];
    int k = s;
    for (; k + 2 <= e; k += 2) {
        int s0 = csr[k], s1 = csr[k + 1];
        uint4 v0 = hn[(size_t)s0 * LPN + l];
        uint4 v1 = hn[(size_t)s1 * LPN + l];
        acc8(a, v0);
        acc8(a, v1);
    }
    if (k < e) acc8(a, hn[(size_t)csr[k] * LPN + l]);

    float dv = dinv[node];
    const float4* b4 = (const float4*)bias;
    float4 bb0 = b4[l * 2], bb1 = b4[l * 2 + 1];
    float o[8];
    o[0] = fmaxf(fmaf(a[0], dv, bb0.x), 0.f);
    o[1] = fmaxf(fmaf(a[1], dv, bb0.y), 0.f);
    o[2] = fmaxf(fmaf(a[2], dv, bb0.z), 0.f);
    o[3] = fmaxf(fmaf(a[3], dv, bb0.w), 0.f);
    o[4] = fmaxf(fmaf(a[4], dv, bb1.x), 0.f);
    o[5] = fmaxf(fmaf(a[5], dv, bb1.y), 0.f);
    o[6] = fmaxf(fmaf(a[6], dv, bb1.z), 0.f);
    o[7] = fmaxf(fmaf(a[7], dv, bb1.w), 0.f);
    uint4 u;
    __half2 p0 = __floats2half2_rn(o[0], o[1]);
    __half2 p1 = __floats2half2_rn(o[2], o[3]);
    __half2 p2 = __floats2half2_rn(o[4], o[5]);
    __half2 p3 = __floats2half2_rn(o[6], o[7]);
    u.x = *(unsigned int*)&p0; u.y = *(unsigned int*)&p1;
    u.z = *(unsigned int*)&p2; u.w = *(unsigned int*)&p3;
    ((uint4*)OUT)[base] = u;
}

// ============ pooling (batch is sorted -> segmented) + MLP head ============

__global__ void k_gstart(const int* __restrict__ batch, int* __restrict__ gstart,
                         int n, int B) {
    int i = blockIdx.x * 256 + threadIdx.x;
    if (i >= n) return;
    int b = batch[i];
    if (i == 0) {
        for (int g = 0; g <= b; ++g) gstart[g] = 0;
    } else {
        int prev = batch[i - 1];
        if (prev != b)
            for (int g = prev + 1; g <= b; ++g) gstart[g] = i;
    }
    if (i == n - 1)
        for (int g = b + 1; g <= B; ++g) gstart[g] = n;
}

__global__ void k_poolhead(const __half* __restrict__ H3, const int* __restrict__ gstart,
                           const float* __restrict__ Wl1, const float* __restrict__ bl1,
                           const float* __restrict__ Wl2, const float* __restrict__ bl2,
                           float* __restrict__ out, int B) {
    __shared__ float sh[4][64];
    __shared__ float shid[4][32];
    int w = threadIdx.x >> 6;
    int lane = threadIdx.x & 63;
    int g = blockIdx.x * 4 + w;
    if (g < B) {
        int s = gstart[g], e = gstart[g + 1];
        float acc = 0.f;
        for (int i = s; i < e; ++i) acc += __half2float(H3[(size_t)i * 64 + lane]);
        float cnt = fmaxf((float)(e - s), 1.f);
        sh[w][lane] = acc / cnt;
    }
    __syncthreads();
    if (g < B && lane < 32) {
        float a = bl1[lane];
        for (int k = 0; k < 64; ++k) a = fmaf(sh[w][k], Wl1[k * 32 + lane], a);
        shid[w][lane] = fmaxf(a, 0.f);
    }
    __syncthreads();
    if (g < B && lane < 10) {
        float a = bl2[lane];
        for (int k = 0; k < 32; ++k) a = fmaf(shid[w][k], Wl2[k * 10 + lane], a);
        out[g * 10 + lane] = a;
    }
}

// ============ launch ============

extern "C" void kernel_launch(void* const* d_in, const int* in_sizes, int n_in,
                              void* d_out, int out_size, void* d_ws, size_t ws_size,
                              hipStream_t stream) {
    const float* x    = (const float*)d_in[0];
    const int*   ei   = (const int*)d_in[1];
    const int*   batch= (const int*)d_in[2];
    const float* W1   = (const float*)d_in[3];
    const float* b1   = (const float*)d_in[4];
    const float* W2   = (const float*)d_in[5];
    const float* b2   = (const float*)d_in[6];
    const float* W3   = (const float*)d_in[7];
    const float* b3   = (const float*)d_in[8];
    const float* Wl1  = (const float*)d_in[9];
    const float* bl1  = (const float*)d_in[10];
    const float* Wl2  = (const float*)d_in[11];
    const float* bl2  = (const float*)d_in[12];

    const int N  = in_sizes[0] / 64;
    const int E  = in_sizes[1] / 2;
    const int B  = out_size / 10;
    const int NB = (N + 15) / 16;          // cursor buckets (dst>>4)
    const int NW = (N + 63) / 64;          // 64-node windows
    const int* srcI = ei;
    const int* dstI = ei + E;

    char* p = (char*)d_ws;
    auto alloc = [&](size_t bytes) {
        char* r = p;
        p += (bytes + 255) & ~(size_t)255;
        return r;
    };
    int*   bcnt      = (int*)alloc((size_t)NB * 4);
    size_t zbytes    = (size_t)(p - (char*)d_ws);      // only bcnt needs zeros
    int*   bstart    = (int*)alloc((size_t)(NB + 1) * 4);
    int*   bcur      = (int*)alloc((size_t)NB * 4);
    int*   packed    = (int*)alloc((size_t)E * 4);
    int*   degcnt    = (int*)alloc((size_t)N * 4);
    float* dinv      = (float*)alloc((size_t)N * 4);
    int*   row_start = (int*)alloc((size_t)(N + 1) * 4);
    int*   bsum      = (int*)alloc(1024 * 4);
    int*   csr       = (int*)alloc((size_t)E * 4);
    int*   gstart    = (int*)alloc((size_t)(B + 1) * 4);
    __half* bufA     = (__half*)alloc((size_t)N * 128 * 2);
    __half* bufB     = (__half*)alloc((size_t)N * 128 * 2);

    hipMemsetAsync(d_ws, 0, zbytes, stream);

    int gE = (E + 255) / 256;
    int gN = (N + 255) / 256;
    k_bhist  <<<gE, 256, 0, stream>>>(dstI, bcnt, E);
    k_bscan  <<<1, 1024, 0, stream>>>(bcnt, bstart, bcur, NB);
    k_binfill<<<gE, 256, 0, stream>>>(srcI, dstI, bcur, packed, E);
    k_bcount <<<NW, 256, 0, stream>>>(packed, bstart, degcnt, dinv, N, NB);
    k_scan1  <<<gN, 256, 0, stream>>>(degcnt, row_start, bsum, N);
    k_scan2  <<<1, 256, 0, stream>>>(bsum, gN);
    k_scan3  <<<gN, 256, 0, stream>>>(row_start, bsum, N, E);
    k_csrfill<<<NW, 256, 0, stream>>>(packed, bstart, row_start, csr, N, NB);

    k_gemm_scale<64, 128, false><<<(N + 15) / 16, 256, 0, stream>>>(x, W1, dinv, bufA, N);
    k_agg_h<128><<<(N + 15) / 16, 256, 0, stream>>>(bufA, csr, row_start, dinv, b1, bufB, N);
    k_gemm_scale<128, 128, true><<<(N + 15) / 16, 256, 0, stream>>>(bufB, W2, dinv, bufA, N);
    k_agg_h<128><<<(N + 15) / 16, 256, 0, stream>>>(bufA, csr, row_start, dinv, b2, bufB, N);
    k_gemm_scale<128, 64, true><<<(N + 15) / 16, 256, 0, stream>>>(bufB, W3, dinv, bufA, N);
    k_agg_h<64><<<(N + 31) / 32, 256, 0, stream>>>(bufA, csr, row_start, dinv, b3, bufB, N);

    k_gstart  <<<gN, 256, 0, stream>>>(batch, gstart, N, B);
    k_poolhead<<<(B + 3) / 4, 256, 0, stream>>>(bufB, gstart, Wl1, bl1, Wl2, bl2,
                                                (float*)d_out, B);
}